// Round 7
// baseline (607.031 us; speedup 1.0000x reference)
//
#include <hip/hip_runtime.h>
#include <math.h>

#define BB 8
#define MTOK 768
#define NTOK 128
#define LTOK 64
#define TT 960          // MTOK+NTOK+LTOK
#define BT 7680         // BB*TT
#define DD 256
#define HH 8
#define HD 32
#define KNN 32
#define FFD 1024
#define NLAYERS 4
#define SCALE_ATT 0.17677669529663687f  // 1/sqrt(32)

typedef __attribute__((ext_vector_type(8))) short bfrag_t;   // 8 bf16 (4 VGPRs)
typedef __attribute__((ext_vector_type(4))) float accfrag_t; // 4 fp32 acc

__device__ __forceinline__ float b2f(unsigned short u) {
  union { unsigned int i; float f; } c; c.i = ((unsigned int)u) << 16; return c.f;
}
__device__ __forceinline__ unsigned short f2b(float f) {
  union { float f; unsigned int i; } c; c.f = f;
  return (unsigned short)((c.i + 0x7fffu + ((c.i >> 16) & 1u)) >> 16);
}
__device__ __forceinline__ float load_elem(const void* p, size_t i, int f) {
  return f ? b2f(((const unsigned short*)p)[i]) : ((const float*)p)[i];
}
// async global->LDS, 16B per lane; LDS dest = uniform base + lane*16
__device__ __forceinline__ void async16(void* lds, const void* g) {
  __builtin_amdgcn_global_load_lds((const __attribute__((address_space(1))) void*)g,
                                   (__attribute__((address_space(3))) void*)lds, 16, 0, 0);
}

// ---------------- dtype detector: bf16 -> flag=1, fp32 -> flag=0 ----------------
__global__ __launch_bounds__(256)
void detect_kernel(const void* tok, int* flag) {
  __shared__ int cnt;
  if (threadIdx.x == 0) cnt = 0;
  __syncthreads();
  const unsigned short* u = (const unsigned short*)tok;
  int ok = 0;
  for (int i = threadIdx.x; i < 1024; i += 256) {
    int e = (u[i] >> 7) & 0xFF;   // bf16 exponent field
    if (e >= 100 && e <= 140) ok++;  // N(0,1) bf16 values land here ~always
  }
  atomicAdd(&cnt, ok);
  __syncthreads();
  if (threadIdx.x == 0) *flag = (cnt >= 922) ? 1 : 0;
}

// ---------------- positions + params -> fp32 (merged) ----------------
#define FB_BQ 0
#define FB_BK 1024
#define FB_BV 2048
#define FB_BO 3072
#define FB_B1 4096
#define FB_B2 8192
#define FB_LN1S 9216
#define FB_LN1B 10240
#define FB_LN2S 11264
#define FB_LN2B 12288
#define FB_TOTAL 13312
struct ParamSrc { const void* p[13]; };  // 0..9 params, 10..12 positions
__global__ __launch_bounds__(256)
void conv_misc_kernel(ParamSrc ps, const int* flag, float* __restrict__ dst,
                      float* __restrict__ posf) {
  int f = *flag;
  if (blockIdx.x < BB) {           // positions
    int b = blockIdx.x;
    for (int t = threadIdx.x; t < TT * 2; t += 256) {
      int tok = t >> 1, c = t & 1;
      const void* p; size_t idx;
      if (tok < MTOK)             { p = ps.p[10]; idx = (size_t)(b * MTOK + tok) * 2 + c; }
      else if (tok < MTOK + NTOK) { p = ps.p[11]; idx = (size_t)(b * NTOK + tok - MTOK) * 2 + c; }
      else                        { p = ps.p[12]; idx = (size_t)(b * LTOK + tok - MTOK - NTOK) * 2 + c; }
      posf[((size_t)b * TT + tok) * 2 + c] = load_elem(p, idx, f);
    }
    return;
  }
  int i = (blockIdx.x - BB) * 256 + threadIdx.x;
  if (i >= FB_TOTAL) return;
  int src; size_t off;
  if (i < 4096)      { src = i >> 10;              off = i & 1023; }
  else if (i < 8192) { src = 4;                    off = i - 4096; }
  else               { src = 5 + ((i - 8192) >> 10); off = (i - 8192) & 1023; }
  dst[i] = load_elem(ps.p[src], off, f);
}

// ---------------- all weight transposes in ONE kernel ----------------
// ops: 0..3 = Wq,Wk,Wv,Wo (256x256, 64 tiles x 4 layers = 256 blocks each)
//      4 = W1 (256x1024, 256 tiles x 4 = 1024), 5 = W2 (1024x256, 1024)
struct WSrc { const void* s[6]; unsigned short* d[6]; };
__global__ __launch_bounds__(256)
void convT_all_kernel(WSrc w, const int* flag) {
  __shared__ unsigned short tile[32][33];
  int f = *flag;
  int id = blockIdx.x;
  int op, R, C; size_t dstStride;
  int tilesXY, layer, txy;
  if (id < 1024)      { op = id >> 8; id &= 255; R = 256; C = 256;
                        dstStride = (op < 3) ? (size_t)3 * DD * DD : (size_t)DD * DD;
                        tilesXY = 64; }
  else if (id < 2048) { op = 4; id -= 1024; R = 256; C = 1024; dstStride = (size_t)DD * FFD; tilesXY = 256; }
  else                { op = 5; id -= 2048; R = 1024; C = 256; dstStride = (size_t)DD * FFD; tilesXY = 256; }
  layer = id / tilesXY; txy = id % tilesXY;
  int tilesX = C >> 5;
  int c0 = (txy % tilesX) * 32, r0 = (txy / tilesX) * 32;
  const void* src = w.s[op];
  unsigned short* d = w.d[op] + (size_t)layer * dstStride
                    + ((op > 0 && op < 3) ? (size_t)op * DD * DD : 0);
  size_t sbase = (size_t)layer * R * C;
  int tx = threadIdx.x & 31, ty = threadIdx.x >> 5;
  for (int rr = ty; rr < 32; rr += 8) {
    size_t si = sbase + (size_t)(r0 + rr) * C + c0 + tx;
    tile[rr][tx] = f ? ((const unsigned short*)src)[si] : f2b(((const float*)src)[si]);
  }
  __syncthreads();
  for (int cc = ty; cc < 32; cc += 8)
    d[(size_t)(c0 + cc) * R + r0 + tx] = tile[tx][cc];
}

// ---------------- prep: positional embedding + stream init ----------------
__global__ __launch_bounds__(256)
void prep_kernel(const void* mt, const void* at, const void* lt,
                 const float* __restrict__ posf, const int* flag,
                 unsigned short* __restrict__ pe_b, float* __restrict__ out_f,
                 unsigned short* __restrict__ out_b, unsigned short* __restrict__ qk_b) {
  int n = blockIdx.x, d = threadIdx.x;
  int b = n / TT, t = n - b * TT;
  int f = *flag;
  const void* src; size_t si;
  if (t < MTOK)              { src = mt; si = (size_t)(b * MTOK + t) * DD + d; }
  else if (t < MTOK + NTOK)  { src = at; si = (size_t)(b * NTOK + (t - MTOK)) * DD + d; }
  else                       { src = lt; si = (size_t)(b * LTOK + (t - MTOK - NTOK)) * DD + d; }
  float x = load_elem(src, si, f);
  float px = posf[((size_t)b * TT + t) * 2 + 0];
  float py = posf[((size_t)b * TT + t) * 2 + 1];
  float coord = (d < 128) ? py : px;   // first 128 dims: y, next 128: x
  int j = d & 127;
  float expo = (float)(2 * (j >> 1)) / 128.0f;
  float dim_t = powf(10000.0f, expo);
  float e = coord * 6.283185307179586f / dim_t;
  float p = (j & 1) ? cosf(e) : sinf(e);
  size_t o = (size_t)n * DD + d;
  pe_b[o] = f2b(p);
  out_f[o] = x;
  out_b[o] = f2b(x);
  qk_b[o] = f2b(x + p);
}

// ---------------- KNN: wave-per-query, 32-bit keys, implicit indices ----------------
__global__ __launch_bounds__(256)
void knn_kernel(const float* __restrict__ posf, int* __restrict__ idx_out) {
  __shared__ float sx[TT], sy[TT];
  int b = blockIdx.x / 240;              // 240 blocks per batch (960/4)
  int qbase = (blockIdx.x % 240) * 4;
  for (int t = threadIdx.x; t < TT; t += 256) {
    sx[t] = posf[((size_t)b * TT + t) * 2 + 0];
    sy[t] = posf[((size_t)b * TT + t) * 2 + 1];
  }
  __syncthreads();
  int wave = threadIdx.x >> 6, lane = threadIdx.x & 63;
  int t = qbase + wave;                  // this wave's query token
  float qx = sx[t], qy = sy[t];
#define MK(c) ({ int j = (c) * 64 + lane;                                    \
                 float dx = qx - sx[j], dy = qy - sy[j];                     \
                 float d2 = __fadd_rn(__fmul_rn(dx, dx), __fmul_rn(dy, dy)); \
                 __float_as_uint(d2); })
  unsigned d0 = MK(0), d1 = MK(1), d2_ = MK(2), d3 = MK(3), d4 = MK(4);
  unsigned d5 = MK(5), d6 = MK(6), d7 = MK(7), d8 = MK(8), d9 = MK(9);
  unsigned d10 = MK(10), d11 = MK(11), d12 = MK(12), d13 = MK(13), d14 = MK(14);
#undef MK
  unsigned res_i = 0;
  for (int i = 0; i < KNN; i++) {
    unsigned bv = d0, bc = 0;
#define UPD(dc, c) { if ((dc) < bv) { bv = (dc); bc = (c); } }
    UPD(d1, 1)  UPD(d2_, 2)  UPD(d3, 3)  UPD(d4, 4)  UPD(d5, 5)
    UPD(d6, 6)  UPD(d7, 7)   UPD(d8, 8)  UPD(d9, 9)  UPD(d10, 10)
    UPD(d11, 11) UPD(d12, 12) UPD(d13, 13) UPD(d14, 14)
#undef UPD
    unsigned gi = (bc << 6) + (unsigned)lane;
#pragma unroll
    for (int o = 32; o > 0; o >>= 1) {
      unsigned od = (unsigned)__shfl_xor((int)bv, o);
      unsigned oi = (unsigned)__shfl_xor((int)gi, o);
      bool take = (od < bv) || (od == bv && oi < gi);
      bv = take ? od : bv;
      gi = take ? oi : gi;
    }
    res_i = ((unsigned)lane == (unsigned)i) ? gi : res_i;
    bool wl = ((unsigned)lane == (gi & 63u));
    unsigned s = gi >> 6;
    d0  = (wl && s == 0)  ? 0xFFFFFFFFu : d0;
    d1  = (wl && s == 1)  ? 0xFFFFFFFFu : d1;
    d2_ = (wl && s == 2)  ? 0xFFFFFFFFu : d2_;
    d3  = (wl && s == 3)  ? 0xFFFFFFFFu : d3;
    d4  = (wl && s == 4)  ? 0xFFFFFFFFu : d4;
    d5  = (wl && s == 5)  ? 0xFFFFFFFFu : d5;
    d6  = (wl && s == 6)  ? 0xFFFFFFFFu : d6;
    d7  = (wl && s == 7)  ? 0xFFFFFFFFu : d7;
    d8  = (wl && s == 8)  ? 0xFFFFFFFFu : d8;
    d9  = (wl && s == 9)  ? 0xFFFFFFFFu : d9;
    d10 = (wl && s == 10) ? 0xFFFFFFFFu : d10;
    d11 = (wl && s == 11) ? 0xFFFFFFFFu : d11;
    d12 = (wl && s == 12) ? 0xFFFFFFFFu : d12;
    d13 = (wl && s == 13) ? 0xFFFFFFFFu : d13;
    d14 = (wl && s == 14) ? 0xFFFFFFFFu : d14;
  }
  if (lane < KNN)
    idx_out[((size_t)(b * TT + t)) * KNN + lane] = b * TT + (int)res_i;
}

// ---------------- GEMM core: 32 rows x 256 cols, software-pipelined ----------------
// B: double-buffered LDS (2x32 KB), async16-staged with XOR chunk swizzle on the
// global address. A: per-lane 16B fragments loaded straight to VGPRs, register-
// double-buffered. One barrier per K-step; prefetch of step s+1 issues right
// after the barrier and flies during compute of step s.
struct GemmSmem {
  union {
    unsigned short Bs[2][256][64];  // 64 KB (the static LDS limit)
    float Cs[32][260];              // 33 KB epilogue scratch (aliases Bs[0])
  };
};

template<int KDIM>
__device__ __forceinline__ void gemm_core(const unsigned short* __restrict__ A,
                                          const unsigned short* __restrict__ Bt, // [256][KDIM]
                                          int m0, GemmSmem& sh, accfrag_t (&acc)[2][4]) {
  const int tid = threadIdx.x;
  const int wave = tid >> 6, lane = tid & 63;
  const int l16 = lane & 15, lq = lane >> 4;
  const int lrow8 = lane >> 3;                    // 0..7: row within 8-row group
  const int lchunk = (lane & 7) ^ lrow8;          // swizzled source chunk 0..7
  accfrag_t z = {0.f, 0.f, 0.f, 0.f};
#pragma unroll
  for (int mt = 0; mt < 2; mt++)
#pragma unroll
    for (int nt = 0; nt < 4; nt++) acc[mt][nt] = z;

  const size_t boff_lane = (size_t)lrow8 * KDIM + lchunk * 8;
  const unsigned short* arow = A + (size_t)(m0 + l16) * KDIM + lq * 8;
  constexpr int NS = KDIM / 64;
  bfrag_t ar[2][4];

#define STAGE_B(s, bi)                                                          \
  {                                                                             \
    _Pragma("unroll")                                                           \
    for (int p = 0; p < 8; p++) {                                               \
      int base_row = (wave * 8 + p) * 8;                                        \
      async16(&sh.Bs[bi][base_row][0],                                          \
              Bt + (size_t)base_row * KDIM + boff_lane + (s) * 64);             \
    }                                                                           \
  }
#define LOAD_A(s, bi)                                                           \
  {                                                                             \
    const unsigned short* ab = arow + (s) * 64;                                 \
    ar[bi][0] = *(const bfrag_t*)(ab);                                          \
    ar[bi][1] = *(const bfrag_t*)(ab + 32);                                     \
    ar[bi][2] = *(const bfrag_t*)(ab + (size_t)16 * KDIM);                      \
    ar[bi][3] = *(const bfrag_t*)(ab + (size_t)16 * KDIM + 32);                 \
  }

  STAGE_B(0, 0);
  LOAD_A(0, 0);
#pragma unroll
  for (int s = 0; s < NS; s++) {
    __syncthreads();                        // drains stage(s)+loadA(s); waves done reading old buf
    if (s + 1 < NS) {
      STAGE_B(s + 1, (s + 1) & 1);
      LOAD_A(s + 1, (s + 1) & 1);
    }
    const int bi = s & 1;
#pragma unroll
    for (int kk = 0; kk < 64; kk += 32) {
      int pos = (((kk >> 3) + lq) ^ (l16 & 7)) * 8;
      bfrag_t a0 = ar[bi][kk >> 5];
      bfrag_t a1 = ar[bi][2 + (kk >> 5)];
#pragma unroll
      for (int nt = 0; nt < 4; nt++) {
        bfrag_t bb = *(const bfrag_t*)(&sh.Bs[bi][wave * 64 + nt * 16 + l16][pos]);
        acc[0][nt] = __builtin_amdgcn_mfma_f32_16x16x32_bf16(a0, bb, acc[0][nt], 0, 0, 0);
        acc[1][nt] = __builtin_amdgcn_mfma_f32_16x16x32_bf16(a1, bb, acc[1][nt], 0, 0, 0);
      }
    }
  }
#undef STAGE_B
#undef LOAD_A
}

// ---------------- fused QKV GEMM (grid.y = 0:Q 1:K 2:V) ----------------
__global__ __launch_bounds__(256)
void gemm_qkv_kernel(const unsigned short* __restrict__ Aqk,
                     const unsigned short* __restrict__ Aout,
                     const unsigned short* __restrict__ WT3,
                     const float* __restrict__ bq,
                     const float* __restrict__ bk,
                     const float* __restrict__ bv,
                     unsigned short* __restrict__ QKV) {
  __shared__ GemmSmem sh;
  int m0 = blockIdx.x * 32;
  int sel = blockIdx.y;
  const unsigned short* A = (sel < 2) ? Aqk : Aout;
  const unsigned short* Bt = WT3 + (size_t)sel * (DD * DD);
  const float* bias = (sel == 0) ? bq : (sel == 1) ? bk : bv;
  unsigned short* C = QKV + (size_t)sel * BT * DD;
  accfrag_t acc[2][4];
  gemm_core<DD>(A, Bt, m0, sh, acc);
  const int tid = threadIdx.x, wave = tid >> 6, lane = tid & 63;
  const int l16 = lane & 15, lq = lane >> 4;
#pragma unroll
  for (int mt = 0; mt < 2; mt++)
#pragma unroll
    for (int nt = 0; nt < 4; nt++) {
      int col = wave * 64 + nt * 16 + l16;
      float bval = bias[col];
#pragma unroll
      for (int r = 0; r < 4; r++) {
        int row = m0 + mt * 16 + lq * 4 + r;
        C[(size_t)row * DD + col] = f2b(acc[mt][nt][r] + bval);
      }
    }
}

// ---------------- plain GEMM + bias + ReLU, bf16 store ----------------
template<int KDIM, bool RELU>
__global__ __launch_bounds__(256)
void gemm_store_kernel(const unsigned short* __restrict__ A,
                       const unsigned short* __restrict__ BtBase,
                       const float* __restrict__ biasBase,
                       unsigned short* __restrict__ C, int Ntot) {
  __shared__ GemmSmem sh;
  int m0 = blockIdx.x * 32;
  int n0 = blockIdx.y * 256;
  const unsigned short* Bt = BtBase + (size_t)n0 * KDIM;
  const float* bias = biasBase + n0;
  accfrag_t acc[2][4];
  gemm_core<KDIM>(A, Bt, m0, sh, acc);
  const int tid = threadIdx.x, wave = tid >> 6, lane = tid & 63;
  const int l16 = lane & 15, lq = lane >> 4;
#pragma unroll
  for (int mt = 0; mt < 2; mt++)
#pragma unroll
    for (int nt = 0; nt < 4; nt++) {
      int col = wave * 64 + nt * 16 + l16;
      float bval = bias[col];
#pragma unroll
      for (int r = 0; r < 4; r++) {
        float v = acc[mt][nt][r] + bval;
        if (RELU) v = fmaxf(v, 0.0f);
        int row = m0 + mt * 16 + lq * 4 + r;
        C[(size_t)row * Ntot + n0 + col] = f2b(v);
      }
    }
}

// ---------------- GEMM + bias + residual + LayerNorm epilogue ----------------
template<int KDIM, bool QK>
__global__ __launch_bounds__(256)
void gemm_ln_kernel(const unsigned short* __restrict__ A,
                    const unsigned short* __restrict__ Bt,
                    const float* __restrict__ bias,
                    float* __restrict__ resid,
                    unsigned short* __restrict__ out_b,
                    unsigned short* __restrict__ qk_b,
                    const unsigned short* __restrict__ pe_b,
                    const float* __restrict__ lns,
                    const float* __restrict__ lnb) {
  __shared__ GemmSmem sh;
  int m0 = blockIdx.x * 32;
  accfrag_t acc[2][4];
  gemm_core<KDIM>(A, Bt, m0, sh, acc);
  const int tid = threadIdx.x, wave = tid >> 6, lane = tid & 63;
  const int l16 = lane & 15, lq = lane >> 4;
  __syncthreads(); // done with Bs; Cs aliases Bs[0]
#pragma unroll
  for (int mt = 0; mt < 2; mt++)
#pragma unroll
    for (int nt = 0; nt < 4; nt++) {
      int col = wave * 64 + nt * 16 + l16;
      float bval = bias[col];
#pragma unroll
      for (int r = 0; r < 4; r++) {
        int lrow = mt * 16 + lq * 4 + r;
        float v = acc[mt][nt][r] + bval + resid[(size_t)(m0 + lrow) * DD + col];
        sh.Cs[lrow][col] = v;
      }
    }
  __syncthreads();
  const float inv = 1.0f / 256.0f;
#pragma unroll
  for (int rr = 0; rr < 8; rr++) {
    int lrow = wave * 8 + rr;
    int grow = m0 + lrow;
    const float4 x = *(const float4*)(&sh.Cs[lrow][lane * 4]);
    float s  = x.x + x.y + x.z + x.w;
    float s2 = x.x * x.x + x.y * x.y + x.z * x.z + x.w * x.w;
#pragma unroll
    for (int o = 32; o > 0; o >>= 1) { s += __shfl_xor(s, o); s2 += __shfl_xor(s2, o); }
    float mu = s * inv;
    float var = s2 * inv - mu * mu;
    float rstd = 1.0f / sqrtf(fmaxf(var, 0.0f) + 1e-5f);
    int c0 = lane * 4;
    float xv[4] = {x.x, x.y, x.z, x.w};
    float ys[4];
#pragma unroll
    for (int c = 0; c < 4; c++)
      ys[c] = (xv[c] - mu) * rstd * lns[c0 + c] + lnb[c0 + c];
    *(float4*)(&resid[(size_t)grow * DD + c0]) = make_float4(ys[0], ys[1], ys[2], ys[3]);
#pragma unroll
    for (int c = 0; c < 4; c++) out_b[(size_t)grow * DD + c0 + c] = f2b(ys[c]);
    if (QK) {
#pragma unroll
      for (int c = 0; c < 4; c++)
        qk_b[(size_t)grow * DD + c0 + c] = f2b(ys[c] + b2f(pe_b[(size_t)grow * DD + c0 + c]));
    }
  }
}

// ---------------- KNN attention (one block per token) ----------------
__global__ __launch_bounds__(256)
void attn_kernel(const unsigned short* __restrict__ QKV,
                 const int* __restrict__ idx,
                 unsigned short* __restrict__ aout) {
  __shared__ unsigned short kn[KNN][DD + 8];
  __shared__ unsigned short vn[KNN][DD + 8];
  __shared__ float qs[DD];
  __shared__ float att[HH][KNN];
  __shared__ int nb[KNN];
  const unsigned short* Q = QKV;
  const unsigned short* K = QKV + (size_t)BT * DD;
  const unsigned short* V = QKV + 2 * (size_t)BT * DD;
  int n = blockIdx.x, tid = threadIdx.x;
  if (tid < KNN) nb[tid] = idx[n * KNN + tid];
  qs[tid] = b2f(Q[(size_t)n * DD + tid]);
  __syncthreads();
#pragma unroll
  for (int p = 0; p < 4; p++) {
    int e = p * 256 + tid;
    int r = e >> 5, c8 = (e & 31) * 8;
    int srow = nb[r];
    *(uint4*)(&kn[r][c8]) = *(const uint4*)(K + (size_t)srow * DD + c8);
    *(uint4*)(&vn[r][c8]) = *(const uint4*)(V + (size_t)srow * DD + c8);
  }
  __syncthreads();
  int h = tid >> 5, kk = tid & 31;
  float dot = 0.0f;
#pragma unroll
  for (int d = 0; d < HD; d++) dot += qs[h * HD + d] * b2f(kn[kk][h * HD + d]);
  float sc = dot * SCALE_ATT;
  float mx = sc;
#pragma unroll
  for (int o = 16; o > 0; o >>= 1) mx = fmaxf(mx, __shfl_xor(mx, o, 32));
  float ex = expf(sc - mx);
  float sm = ex;
#pragma unroll
  for (int o = 16; o > 0; o >>= 1) sm += __shfl_xor(sm, o, 32);
  att[h][kk] = ex / sm;
  __syncthreads();
  int d = kk;
  float oacc = 0.0f;
#pragma unroll
  for (int k2 = 0; k2 < KNN; k2++) oacc += att[h][k2] * b2f(vn[k2][h * HD + d]);
  aout[(size_t)n * DD + tid] = f2b(oacc);
}

// ---------------- final write (map | agent | light blocks) ----------------
__global__ __launch_bounds__(256)
void writeout_kernel(const float* __restrict__ out_f, void* __restrict__ dst,
                     const int* flag) {
  int n = blockIdx.x, d = threadIdx.x;
  int b = n / TT, t = n - b * TT;
  size_t o;
  if (t < MTOK)             o = (size_t)(b * MTOK + t) * DD + d;
  else if (t < MTOK + NTOK) o = (size_t)BB * MTOK * DD + (size_t)(b * NTOK + (t - MTOK)) * DD + d;
  else                      o = (size_t)BB * MTOK * DD + (size_t)BB * NTOK * DD
                              + (size_t)(b * LTOK + (t - MTOK - NTOK)) * DD + d;
  float v = out_f[(size_t)n * DD + d];
  if (*flag) ((unsigned short*)dst)[o] = f2b(v);
  else       ((float*)dst)[o] = v;
}

// ---------------- launcher ----------------
extern "C" void kernel_launch(void* const* d_in, const int* in_sizes, int n_in,
                              void* d_out, int out_size, void* d_ws, size_t ws_size,
                              hipStream_t stream) {
  const void* map_tok   = d_in[0];
  const void* agent_tok = d_in[1];
  const void* light_tok = d_in[2];
  const void* map_pos   = d_in[3];
  const void* agent_pos = d_in[4];
  const void* light_pos = d_in[5];
  // d_in[6..8]: valid masks (all true) -- unused
  const void* Wq  = d_in[9];
  const void* bq  = d_in[10];
  const void* Wk  = d_in[11];
  const void* bk  = d_in[12];
  const void* Wv  = d_in[13];
  const void* bv  = d_in[14];
  const void* Wo  = d_in[15];
  const void* bo  = d_in[16];
  const void* W1  = d_in[17];
  const void* b1  = d_in[18];
  const void* W2  = d_in[19];
  const void* b2  = d_in[20];
  const void* ln1s = d_in[21];
  const void* ln1b = d_in[22];
  const void* ln2s = d_in[23];
  const void* ln2b = d_in[24];

  size_t off = 0;
  char* base = (char*)d_ws;
  auto take = [&](size_t bytes) { char* p = base + off; off += (bytes + 255) & ~(size_t)255; return (void*)p; };
  int*   flag  = (int*)take(256);
  float* posf  = (float*)take((size_t)BT * 2 * 4);
  float* pbuf  = (float*)take((size_t)FB_TOTAL * 4);
  unsigned short* pe_b = (unsigned short*)take((size_t)BT * DD * 2);
  float* out_f = (float*)take((size_t)BT * DD * 4);
  unsigned short* out_b = (unsigned short*)take((size_t)BT * DD * 2);
  unsigned short* qk_b  = (unsigned short*)take((size_t)BT * DD * 2);
  unsigned short* big   = (unsigned short*)take((size_t)BT * FFD * 2); // hbuf; QKV aliases front
  unsigned short* QKV     = big;
  unsigned short* attnout = big;            // overwrites Q region (safe: per-block self-write)
  unsigned short* hbuf    = big;
  int* idxb = (int*)take((size_t)BT * KNN * 4);
  unsigned short* WqkvT = (unsigned short*)take((size_t)NLAYERS * 3 * DD * DD * 2);
  unsigned short* WoT   = (unsigned short*)take((size_t)NLAYERS * DD * DD * 2);
  unsigned short* W1T   = (unsigned short*)take((size_t)NLAYERS * DD * FFD * 2);
  unsigned short* W2T   = (unsigned short*)take((size_t)NLAYERS * DD * FFD * 2);

  detect_kernel<<<1, 256, 0, stream>>>(map_tok, flag);
  ParamSrc ps; ps.p[0]=bq; ps.p[1]=bk; ps.p[2]=bv; ps.p[3]=bo; ps.p[4]=b1;
  ps.p[5]=b2; ps.p[6]=ln1s; ps.p[7]=ln1b; ps.p[8]=ln2s; ps.p[9]=ln2b;
  ps.p[10]=map_pos; ps.p[11]=agent_pos; ps.p[12]=light_pos;
  conv_misc_kernel<<<BB + (FB_TOTAL + 255) / 256, 256, 0, stream>>>(ps, flag, pbuf, posf);

  WSrc w;
  w.s[0]=Wq; w.s[1]=Wk; w.s[2]=Wv; w.s[3]=Wo; w.s[4]=W1; w.s[5]=W2;
  w.d[0]=WqkvT; w.d[1]=WqkvT; w.d[2]=WqkvT; w.d[3]=WoT; w.d[4]=W1T; w.d[5]=W2T;
  convT_all_kernel<<<3072, 256, 0, stream>>>(w, flag);

  prep_kernel<<<BT, 256, 0, stream>>>(map_tok, agent_tok, light_tok, posf, flag,
                                      pe_b, out_f, out_b, qk_b);
  knn_kernel<<<1920, 256, 0, stream>>>(posf, idxb);

  const int RB = BT / 32; // 240 row blocks
  for (int l = 0; l < NLAYERS; l++) {
    gemm_qkv_kernel<<<dim3(RB, 3), 256, 0, stream>>>(
        qk_b, out_b, WqkvT + (size_t)l * 3 * DD * DD,
        pbuf + FB_BQ + l * DD, pbuf + FB_BK + l * DD, pbuf + FB_BV + l * DD, QKV);
    attn_kernel<<<BT, 256, 0, stream>>>(QKV, idxb, attnout);
    gemm_ln_kernel<DD, false><<<RB, 256, 0, stream>>>(
        attnout, WoT + (size_t)l * DD * DD, pbuf + FB_BO + l * DD,
        out_f, out_b, qk_b, pe_b, pbuf + FB_LN1S + l * DD, pbuf + FB_LN1B + l * DD);
    gemm_store_kernel<DD, true><<<dim3(RB, 4), 256, 0, stream>>>(
        out_b, W1T + (size_t)l * DD * FFD, pbuf + FB_B1 + l * FFD, hbuf, FFD);
    gemm_ln_kernel<FFD, true><<<RB, 256, 0, stream>>>(
        hbuf, W2T + (size_t)l * DD * FFD, pbuf + FB_B2 + l * DD,
        out_f, out_b, qk_b, pe_b, pbuf + FB_LN2S + l * DD, pbuf + FB_LN2B + l * DD);
  }

  writeout_kernel<<<BT, 256, 0, stream>>>(out_f, d_out, flag);
}

// Round 8
// 592.886 us; speedup vs baseline: 1.0239x; 1.0239x over previous
//
#include <hip/hip_runtime.h>
#include <math.h>

#define BB 8
#define MTOK 768
#define NTOK 128
#define LTOK 64
#define TT 960          // MTOK+NTOK+LTOK
#define BT 7680         // BB*TT
#define DD 256
#define HH 8
#define HD 32
#define KNN 32
#define FFD 1024
#define NLAYERS 4
#define SCALE_ATT 0.17677669529663687f  // 1/sqrt(32)

typedef __attribute__((ext_vector_type(8))) short bfrag_t;   // 8 bf16 (4 VGPRs)
typedef __attribute__((ext_vector_type(4))) float accfrag_t; // 4 fp32 acc

__device__ __forceinline__ float b2f(unsigned short u) {
  union { unsigned int i; float f; } c; c.i = ((unsigned int)u) << 16; return c.f;
}
__device__ __forceinline__ unsigned short f2b(float f) {
  union { float f; unsigned int i; } c; c.f = f;
  return (unsigned short)((c.i + 0x7fffu + ((c.i >> 16) & 1u)) >> 16);
}
__device__ __forceinline__ float load_elem(const void* p, size_t i, int f) {
  return f ? b2f(((const unsigned short*)p)[i]) : ((const float*)p)[i];
}
// async global->LDS, 16B per lane; LDS dest = uniform base + lane*16
__device__ __forceinline__ void async16(void* lds, const void* g) {
  __builtin_amdgcn_global_load_lds((const __attribute__((address_space(1))) void*)g,
                                   (__attribute__((address_space(3))) void*)lds, 16, 0, 0);
}
// scene->XCD swizzle: blocks land on XCD (blockIdx % 8); keep scene b on XCD b.
__device__ __forceinline__ int swiz_m0(int blk)  { return (blk & 7) * TT + (blk >> 3) * 32; } // 240 blocks
__device__ __forceinline__ int swiz_tok(int blk) { return (blk & 7) * TT + (blk >> 3); }      // 7680 blocks

// ---------------- dtype detector: bf16 -> flag=1, fp32 -> flag=0 ----------------
__global__ __launch_bounds__(256)
void detect_kernel(const void* tok, int* flag) {
  __shared__ int cnt;
  if (threadIdx.x == 0) cnt = 0;
  __syncthreads();
  const unsigned short* u = (const unsigned short*)tok;
  int ok = 0;
  for (int i = threadIdx.x; i < 1024; i += 256) {
    int e = (u[i] >> 7) & 0xFF;   // bf16 exponent field
    if (e >= 100 && e <= 140) ok++;  // N(0,1) bf16 values land here ~always
  }
  atomicAdd(&cnt, ok);
  __syncthreads();
  if (threadIdx.x == 0) *flag = (cnt >= 922) ? 1 : 0;
}

// ---------------- positions + params -> fp32 (merged) ----------------
#define FB_BQ 0
#define FB_BK 1024
#define FB_BV 2048
#define FB_BO 3072
#define FB_B1 4096
#define FB_B2 8192
#define FB_LN1S 9216
#define FB_LN1B 10240
#define FB_LN2S 11264
#define FB_LN2B 12288
#define FB_TOTAL 13312
struct ParamSrc { const void* p[13]; };  // 0..9 params, 10..12 positions
__global__ __launch_bounds__(256)
void conv_misc_kernel(ParamSrc ps, const int* flag, float* __restrict__ dst,
                      float* __restrict__ posf) {
  int f = *flag;
  if (blockIdx.x < BB) {           // positions
    int b = blockIdx.x;
    for (int t = threadIdx.x; t < TT * 2; t += 256) {
      int tok = t >> 1, c = t & 1;
      const void* p; size_t idx;
      if (tok < MTOK)             { p = ps.p[10]; idx = (size_t)(b * MTOK + tok) * 2 + c; }
      else if (tok < MTOK + NTOK) { p = ps.p[11]; idx = (size_t)(b * NTOK + tok - MTOK) * 2 + c; }
      else                        { p = ps.p[12]; idx = (size_t)(b * LTOK + tok - MTOK - NTOK) * 2 + c; }
      posf[((size_t)b * TT + tok) * 2 + c] = load_elem(p, idx, f);
    }
    return;
  }
  int i = (blockIdx.x - BB) * 256 + threadIdx.x;
  if (i >= FB_TOTAL) return;
  int src; size_t off;
  if (i < 4096)      { src = i >> 10;              off = i & 1023; }
  else if (i < 8192) { src = 4;                    off = i - 4096; }
  else               { src = 5 + ((i - 8192) >> 10); off = (i - 8192) & 1023; }
  dst[i] = load_elem(ps.p[src], off, f);
}

// ---------------- all weight transposes in ONE kernel ----------------
struct WSrc { const void* s[6]; unsigned short* d[6]; };
__global__ __launch_bounds__(256)
void convT_all_kernel(WSrc w, const int* flag) {
  __shared__ unsigned short tile[32][33];
  int f = *flag;
  int id = blockIdx.x;
  int op, R, C; size_t dstStride;
  int tilesXY, layer, txy;
  if (id < 1024)      { op = id >> 8; id &= 255; R = 256; C = 256;
                        dstStride = (op < 3) ? (size_t)3 * DD * DD : (size_t)DD * DD;
                        tilesXY = 64; }
  else if (id < 2048) { op = 4; id -= 1024; R = 256; C = 1024; dstStride = (size_t)DD * FFD; tilesXY = 256; }
  else                { op = 5; id -= 2048; R = 1024; C = 256; dstStride = (size_t)DD * FFD; tilesXY = 256; }
  layer = id / tilesXY; txy = id % tilesXY;
  int tilesX = C >> 5;
  int c0 = (txy % tilesX) * 32, r0 = (txy / tilesX) * 32;
  const void* src = w.s[op];
  unsigned short* d = w.d[op] + (size_t)layer * dstStride
                    + ((op > 0 && op < 3) ? (size_t)op * DD * DD : 0);
  size_t sbase = (size_t)layer * R * C;
  int tx = threadIdx.x & 31, ty = threadIdx.x >> 5;
  for (int rr = ty; rr < 32; rr += 8) {
    size_t si = sbase + (size_t)(r0 + rr) * C + c0 + tx;
    tile[rr][tx] = f ? ((const unsigned short*)src)[si] : f2b(((const float*)src)[si]);
  }
  __syncthreads();
  for (int cc = ty; cc < 32; cc += 8)
    d[(size_t)(c0 + cc) * R + r0 + tx] = tile[tx][cc];
}

// ---------------- prep: positional embedding + stream init ----------------
__global__ __launch_bounds__(256)
void prep_kernel(const void* mt, const void* at, const void* lt,
                 const float* __restrict__ posf, const int* flag,
                 unsigned short* __restrict__ pe_b, float* __restrict__ out_f,
                 unsigned short* __restrict__ out_b, unsigned short* __restrict__ qk_b) {
  int n = swiz_tok(blockIdx.x), d = threadIdx.x;
  int b = n / TT, t = n - b * TT;
  int f = *flag;
  const void* src; size_t si;
  if (t < MTOK)              { src = mt; si = (size_t)(b * MTOK + t) * DD + d; }
  else if (t < MTOK + NTOK)  { src = at; si = (size_t)(b * NTOK + (t - MTOK)) * DD + d; }
  else                       { src = lt; si = (size_t)(b * LTOK + (t - MTOK - NTOK)) * DD + d; }
  float x = load_elem(src, si, f);
  float px = posf[((size_t)b * TT + t) * 2 + 0];
  float py = posf[((size_t)b * TT + t) * 2 + 1];
  float coord = (d < 128) ? py : px;   // first 128 dims: y, next 128: x
  int j = d & 127;
  float expo = (float)(2 * (j >> 1)) / 128.0f;
  float dim_t = powf(10000.0f, expo);
  float e = coord * 6.283185307179586f / dim_t;
  float p = (j & 1) ? cosf(e) : sinf(e);
  size_t o = (size_t)n * DD + d;
  pe_b[o] = f2b(p);
  out_f[o] = x;
  out_b[o] = f2b(x);
  qk_b[o] = f2b(x + p);
}

// ---------------- KNN: wave-per-query, 32-bit keys, implicit indices ----------------
__global__ __launch_bounds__(256)
void knn_kernel(const float* __restrict__ posf, int* __restrict__ idx_out) {
  __shared__ float sx[TT], sy[TT];
  int b = blockIdx.x & 7;                     // scene -> XCD
  int qbase = (blockIdx.x >> 3) * 4;          // 240 per scene
  for (int t = threadIdx.x; t < TT; t += 256) {
    sx[t] = posf[((size_t)b * TT + t) * 2 + 0];
    sy[t] = posf[((size_t)b * TT + t) * 2 + 1];
  }
  __syncthreads();
  int wave = threadIdx.x >> 6, lane = threadIdx.x & 63;
  int t = qbase + wave;                  // this wave's query token
  float qx = sx[t], qy = sy[t];
#define MK(c) ({ int j = (c) * 64 + lane;                                    \
                 float dx = qx - sx[j], dy = qy - sy[j];                     \
                 float d2 = __fadd_rn(__fmul_rn(dx, dx), __fmul_rn(dy, dy)); \
                 __float_as_uint(d2); })
  unsigned d0 = MK(0), d1 = MK(1), d2_ = MK(2), d3 = MK(3), d4 = MK(4);
  unsigned d5 = MK(5), d6 = MK(6), d7 = MK(7), d8 = MK(8), d9 = MK(9);
  unsigned d10 = MK(10), d11 = MK(11), d12 = MK(12), d13 = MK(13), d14 = MK(14);
#undef MK
  unsigned res_i = 0;
  for (int i = 0; i < KNN; i++) {
    unsigned bv = d0, bc = 0;
#define UPD(dc, c) { if ((dc) < bv) { bv = (dc); bc = (c); } }
    UPD(d1, 1)  UPD(d2_, 2)  UPD(d3, 3)  UPD(d4, 4)  UPD(d5, 5)
    UPD(d6, 6)  UPD(d7, 7)   UPD(d8, 8)  UPD(d9, 9)  UPD(d10, 10)
    UPD(d11, 11) UPD(d12, 12) UPD(d13, 13) UPD(d14, 14)
#undef UPD
    unsigned gi = (bc << 6) + (unsigned)lane;
#pragma unroll
    for (int o = 32; o > 0; o >>= 1) {
      unsigned od = (unsigned)__shfl_xor((int)bv, o);
      unsigned oi = (unsigned)__shfl_xor((int)gi, o);
      bool take = (od < bv) || (od == bv && oi < gi);
      bv = take ? od : bv;
      gi = take ? oi : gi;
    }
    res_i = ((unsigned)lane == (unsigned)i) ? gi : res_i;
    bool wl = ((unsigned)lane == (gi & 63u));
    unsigned s = gi >> 6;
    d0  = (wl && s == 0)  ? 0xFFFFFFFFu : d0;
    d1  = (wl && s == 1)  ? 0xFFFFFFFFu : d1;
    d2_ = (wl && s == 2)  ? 0xFFFFFFFFu : d2_;
    d3  = (wl && s == 3)  ? 0xFFFFFFFFu : d3;
    d4  = (wl && s == 4)  ? 0xFFFFFFFFu : d4;
    d5  = (wl && s == 5)  ? 0xFFFFFFFFu : d5;
    d6  = (wl && s == 6)  ? 0xFFFFFFFFu : d6;
    d7  = (wl && s == 7)  ? 0xFFFFFFFFu : d7;
    d8  = (wl && s == 8)  ? 0xFFFFFFFFu : d8;
    d9  = (wl && s == 9)  ? 0xFFFFFFFFu : d9;
    d10 = (wl && s == 10) ? 0xFFFFFFFFu : d10;
    d11 = (wl && s == 11) ? 0xFFFFFFFFu : d11;
    d12 = (wl && s == 12) ? 0xFFFFFFFFu : d12;
    d13 = (wl && s == 13) ? 0xFFFFFFFFu : d13;
    d14 = (wl && s == 14) ? 0xFFFFFFFFu : d14;
  }
  if (lane < KNN)
    idx_out[((size_t)(b * TT + t)) * KNN + lane] = b * TT + (int)res_i;
}

// ---------------- GEMM core: 32 rows x 256 cols, bf16 MFMA (R6 version) ----------------
// LDS unpadded (64-short rows). Staged via global_load_lds width=16 with an
// XOR chunk swizzle applied on the GLOBAL address (per-lane).
struct GemmSmem {
  union {
    struct { unsigned short As[32][64]; unsigned short Bs[256][64]; } s; // 36 KB
    float Cs[32][260];                                                   // 33 KB
  };
};

template<int KDIM>
__device__ __forceinline__ void gemm_core(const unsigned short* __restrict__ A,
                                          const unsigned short* __restrict__ Bt, // [256][KDIM]
                                          int m0, GemmSmem& sh, accfrag_t (&acc)[2][4]) {
  const int tid = threadIdx.x;
  const int wave = tid >> 6, lane = tid & 63;
  const int l16 = lane & 15, lq = lane >> 4;
  const int lrow8 = lane >> 3;                    // 0..7: row within 8-row group
  const int lchunk = (lane & 7) ^ lrow8;          // swizzled source chunk 0..7
  accfrag_t z = {0.f, 0.f, 0.f, 0.f};
#pragma unroll
  for (int mt = 0; mt < 2; mt++)
#pragma unroll
    for (int nt = 0; nt < 4; nt++) acc[mt][nt] = z;

  const size_t aoff = (size_t)(m0 + wave * 8 + lrow8) * KDIM + lchunk * 8;
  const size_t boff_lane = (size_t)lrow8 * KDIM + lchunk * 8;

  for (int k0 = 0; k0 < KDIM; k0 += 64) {
    __syncthreads();  // all waves done reading previous tile
    async16(&sh.s.As[wave * 8][0], A + aoff + k0);
#pragma unroll
    for (int p = 0; p < 8; p++) {
      int base_row = (wave * 8 + p) * 8;
      async16(&sh.s.Bs[base_row][0], Bt + (size_t)base_row * KDIM + boff_lane + k0);
    }
    __syncthreads();  // drains vmcnt -> staged data visible
#pragma unroll
    for (int kk = 0; kk < 64; kk += 32) {
      int pos = (((kk >> 3) + lq) ^ (l16 & 7)) * 8;
      bfrag_t a0 = *(const bfrag_t*)(&sh.s.As[l16][pos]);
      bfrag_t a1 = *(const bfrag_t*)(&sh.s.As[16 + l16][pos]);
#pragma unroll
      for (int nt = 0; nt < 4; nt++) {
        bfrag_t bb = *(const bfrag_t*)(&sh.s.Bs[wave * 64 + nt * 16 + l16][pos]);
        acc[0][nt] = __builtin_amdgcn_mfma_f32_16x16x32_bf16(a0, bb, acc[0][nt], 0, 0, 0);
        acc[1][nt] = __builtin_amdgcn_mfma_f32_16x16x32_bf16(a1, bb, acc[1][nt], 0, 0, 0);
      }
    }
  }
}

// ---------------- fused QKV GEMM (grid.y = 0:Q 1:K 2:V) ----------------
__global__ __launch_bounds__(256)
void gemm_qkv_kernel(const unsigned short* __restrict__ Aqk,
                     const unsigned short* __restrict__ Aout,
                     const unsigned short* __restrict__ WT3,
                     const float* __restrict__ bq,
                     const float* __restrict__ bk,
                     const float* __restrict__ bv,
                     unsigned short* __restrict__ QKV) {
  __shared__ GemmSmem sh;
  int m0 = swiz_m0(blockIdx.x);
  int sel = blockIdx.y;
  const unsigned short* A = (sel < 2) ? Aqk : Aout;
  const unsigned short* Bt = WT3 + (size_t)sel * (DD * DD);
  const float* bias = (sel == 0) ? bq : (sel == 1) ? bk : bv;
  unsigned short* C = QKV + (size_t)sel * BT * DD;
  accfrag_t acc[2][4];
  gemm_core<DD>(A, Bt, m0, sh, acc);
  const int tid = threadIdx.x, wave = tid >> 6, lane = tid & 63;
  const int l16 = lane & 15, lq = lane >> 4;
#pragma unroll
  for (int mt = 0; mt < 2; mt++)
#pragma unroll
    for (int nt = 0; nt < 4; nt++) {
      int col = wave * 64 + nt * 16 + l16;
      float bval = bias[col];
#pragma unroll
      for (int r = 0; r < 4; r++) {
        int row = m0 + mt * 16 + lq * 4 + r;
        C[(size_t)row * DD + col] = f2b(acc[mt][nt][r] + bval);
      }
    }
}

// ---------------- plain GEMM + bias + ReLU, bf16 store ----------------
template<int KDIM, bool RELU>
__global__ __launch_bounds__(256)
void gemm_store_kernel(const unsigned short* __restrict__ A,
                       const unsigned short* __restrict__ BtBase,
                       const float* __restrict__ biasBase,
                       unsigned short* __restrict__ C, int Ntot) {
  __shared__ GemmSmem sh;
  int m0 = swiz_m0(blockIdx.x);
  int n0 = blockIdx.y * 256;
  const unsigned short* Bt = BtBase + (size_t)n0 * KDIM;
  const float* bias = biasBase + n0;
  accfrag_t acc[2][4];
  gemm_core<KDIM>(A, Bt, m0, sh, acc);
  const int tid = threadIdx.x, wave = tid >> 6, lane = tid & 63;
  const int l16 = lane & 15, lq = lane >> 4;
#pragma unroll
  for (int mt = 0; mt < 2; mt++)
#pragma unroll
    for (int nt = 0; nt < 4; nt++) {
      int col = wave * 64 + nt * 16 + l16;
      float bval = bias[col];
#pragma unroll
      for (int r = 0; r < 4; r++) {
        float v = acc[mt][nt][r] + bval;
        if (RELU) v = fmaxf(v, 0.0f);
        int row = m0 + mt * 16 + lq * 4 + r;
        C[(size_t)row * Ntot + n0 + col] = f2b(v);
      }
    }
}

// ---------------- GEMM + bias + residual + LayerNorm epilogue ----------------
template<int KDIM, bool QK>
__global__ __launch_bounds__(256)
void gemm_ln_kernel(const unsigned short* __restrict__ A,
                    const unsigned short* __restrict__ Bt,
                    const float* __restrict__ bias,
                    float* __restrict__ resid,
                    unsigned short* __restrict__ out_b,
                    unsigned short* __restrict__ qk_b,
                    const unsigned short* __restrict__ pe_b,
                    const float* __restrict__ lns,
                    const float* __restrict__ lnb) {
  __shared__ GemmSmem sh;
  int m0 = swiz_m0(blockIdx.x);
  accfrag_t acc[2][4];
  gemm_core<KDIM>(A, Bt, m0, sh, acc);
  const int tid = threadIdx.x, wave = tid >> 6, lane = tid & 63;
  const int l16 = lane & 15, lq = lane >> 4;
  __syncthreads(); // done with As/Bs; Cs aliases them
#pragma unroll
  for (int mt = 0; mt < 2; mt++)
#pragma unroll
    for (int nt = 0; nt < 4; nt++) {
      int col = wave * 64 + nt * 16 + l16;
      float bval = bias[col];
#pragma unroll
      for (int r = 0; r < 4; r++) {
        int lrow = mt * 16 + lq * 4 + r;
        float v = acc[mt][nt][r] + bval + resid[(size_t)(m0 + lrow) * DD + col];
        sh.Cs[lrow][col] = v;
      }
    }
  __syncthreads();
  const float inv = 1.0f / 256.0f;
#pragma unroll
  for (int rr = 0; rr < 8; rr++) {
    int lrow = wave * 8 + rr;
    int grow = m0 + lrow;
    const float4 x = *(const float4*)(&sh.Cs[lrow][lane * 4]);
    float s  = x.x + x.y + x.z + x.w;
    float s2 = x.x * x.x + x.y * x.y + x.z * x.z + x.w * x.w;
#pragma unroll
    for (int o = 32; o > 0; o >>= 1) { s += __shfl_xor(s, o); s2 += __shfl_xor(s2, o); }
    float mu = s * inv;
    float var = s2 * inv - mu * mu;
    float rstd = 1.0f / sqrtf(fmaxf(var, 0.0f) + 1e-5f);
    int c0 = lane * 4;
    float xv[4] = {x.x, x.y, x.z, x.w};
    float ys[4];
#pragma unroll
    for (int c = 0; c < 4; c++)
      ys[c] = (xv[c] - mu) * rstd * lns[c0 + c] + lnb[c0 + c];
    *(float4*)(&resid[(size_t)grow * DD + c0]) = make_float4(ys[0], ys[1], ys[2], ys[3]);
#pragma unroll
    for (int c = 0; c < 4; c++) out_b[(size_t)grow * DD + c0 + c] = f2b(ys[c]);
    if (QK) {
#pragma unroll
      for (int c = 0; c < 4; c++)
        qk_b[(size_t)grow * DD + c0 + c] = f2b(ys[c] + b2f(pe_b[(size_t)grow * DD + c0 + c]));
    }
  }
}

// ---------------- KNN attention (one block per token, scene->XCD swizzled) ----------------
__global__ __launch_bounds__(256)
void attn_kernel(const unsigned short* __restrict__ QKV,
                 const int* __restrict__ idx,
                 unsigned short* __restrict__ aout) {
  __shared__ unsigned short kn[KNN][DD + 8];
  __shared__ unsigned short vn[KNN][DD + 8];
  __shared__ float qs[DD];
  __shared__ float att[HH][KNN];
  __shared__ int nb[KNN];
  const unsigned short* Q = QKV;
  const unsigned short* K = QKV + (size_t)BT * DD;
  const unsigned short* V = QKV + 2 * (size_t)BT * DD;
  int n = swiz_tok(blockIdx.x), tid = threadIdx.x;
  if (tid < KNN) nb[tid] = idx[n * KNN + tid];
  qs[tid] = b2f(Q[(size_t)n * DD + tid]);
  __syncthreads();
#pragma unroll
  for (int p = 0; p < 4; p++) {
    int e = p * 256 + tid;
    int r = e >> 5, c8 = (e & 31) * 8;
    int srow = nb[r];
    *(uint4*)(&kn[r][c8]) = *(const uint4*)(K + (size_t)srow * DD + c8);
    *(uint4*)(&vn[r][c8]) = *(const uint4*)(V + (size_t)srow * DD + c8);
  }
  __syncthreads();
  int h = tid >> 5, kk = tid & 31;
  float dot = 0.0f;
#pragma unroll
  for (int d = 0; d < HD; d++) dot += qs[h * HD + d] * b2f(kn[kk][h * HD + d]);
  float sc = dot * SCALE_ATT;
  float mx = sc;
#pragma unroll
  for (int o = 16; o > 0; o >>= 1) mx = fmaxf(mx, __shfl_xor(mx, o, 32));
  float ex = expf(sc - mx);
  float sm = ex;
#pragma unroll
  for (int o = 16; o > 0; o >>= 1) sm += __shfl_xor(sm, o, 32);
  att[h][kk] = ex / sm;
  __syncthreads();
  int d = kk;
  float oacc = 0.0f;
#pragma unroll
  for (int k2 = 0; k2 < KNN; k2++) oacc += att[h][k2] * b2f(vn[k2][h * HD + d]);
  aout[(size_t)n * DD + tid] = f2b(oacc);
}

// ---------------- final write (map | agent | light blocks) ----------------
__global__ __launch_bounds__(256)
void writeout_kernel(const float* __restrict__ out_f, void* __restrict__ dst,
                     const int* flag) {
  int n = swiz_tok(blockIdx.x), d = threadIdx.x;
  int b = n / TT, t = n - b * TT;
  size_t o;
  if (t < MTOK)             o = (size_t)(b * MTOK + t) * DD + d;
  else if (t < MTOK + NTOK) o = (size_t)BB * MTOK * DD + (size_t)(b * NTOK + (t - MTOK)) * DD + d;
  else                      o = (size_t)BB * MTOK * DD + (size_t)BB * NTOK * DD
                              + (size_t)(b * LTOK + (t - MTOK - NTOK)) * DD + d;
  float v = out_f[(size_t)n * DD + d];
  if (*flag) ((unsigned short*)dst)[o] = f2b(v);
  else       ((float*)dst)[o] = v;
}

// ---------------- launcher ----------------
extern "C" void kernel_launch(void* const* d_in, const int* in_sizes, int n_in,
                              void* d_out, int out_size, void* d_ws, size_t ws_size,
                              hipStream_t stream) {
  const void* map_tok   = d_in[0];
  const void* agent_tok = d_in[1];
  const void* light_tok = d_in[2];
  const void* map_pos   = d_in[3];
  const void* agent_pos = d_in[4];
  const void* light_pos = d_in[5];
  // d_in[6..8]: valid masks (all true) -- unused
  const void* Wq  = d_in[9];
  const void* bq  = d_in[10];
  const void* Wk  = d_in[11];
  const void* bk  = d_in[12];
  const void* Wv  = d_in[13];
  const void* bv  = d_in[14];
  const void* Wo  = d_in[15];
  const void* bo  = d_in[16];
  const void* W1  = d_in[17];
  const void* b1  = d_in[18];
  const void* W2  = d_in[19];
  const void* b2  = d_in[20];
  const void* ln1s = d_in[21];
  const void* ln1b = d_in[22];
  const void* ln2s = d_in[23];
  const void* ln2b = d_in[24];

  size_t off = 0;
  char* base = (char*)d_ws;
  auto take = [&](size_t bytes) { char* p = base + off; off += (bytes + 255) & ~(size_t)255; return (void*)p; };
  int*   flag  = (int*)take(256);
  float* posf  = (float*)take((size_t)BT * 2 * 4);
  float* pbuf  = (float*)take((size_t)FB_TOTAL * 4);
  unsigned short* pe_b = (unsigned short*)take((size_t)BT * DD * 2);
  float* out_f = (float*)take((size_t)BT * DD * 4);
  unsigned short* out_b = (unsigned short*)take((size_t)BT * DD * 2);
  unsigned short* qk_b  = (unsigned short*)take((size_t)BT * DD * 2);
  unsigned short* big   = (unsigned short*)take((size_t)BT * FFD * 2); // hbuf; QKV aliases front
  unsigned short* QKV     = big;
  unsigned short* attnout = big;            // overwrites Q region (safe: per-block self-write)
  unsigned short* hbuf    = big;
  int* idxb = (int*)take((size_t)BT * KNN * 4);
  unsigned short* WqkvT = (unsigned short*)take((size_t)NLAYERS * 3 * DD * DD * 2);
  unsigned short* WoT   = (unsigned short*)take((size_t)NLAYERS * DD * DD * 2);
  unsigned short* W1T   = (unsigned short*)take((size_t)NLAYERS * DD * FFD * 2);
  unsigned short* W2T   = (unsigned short*)take((size_t)NLAYERS * DD * FFD * 2);

  detect_kernel<<<1, 256, 0, stream>>>(map_tok, flag);
  ParamSrc ps; ps.p[0]=bq; ps.p[1]=bk; ps.p[2]=bv; ps.p[3]=bo; ps.p[4]=b1;
  ps.p[5]=b2; ps.p[6]=ln1s; ps.p[7]=ln1b; ps.p[8]=ln2s; ps.p[9]=ln2b;
  ps.p[10]=map_pos; ps.p[11]=agent_pos; ps.p[12]=light_pos;
  conv_misc_kernel<<<BB + (FB_TOTAL + 255) / 256, 256, 0, stream>>>(ps, flag, pbuf, posf);

  WSrc w;
  w.s[0]=Wq; w.s[1]=Wk; w.s[2]=Wv; w.s[3]=Wo; w.s[4]=W1; w.s[5]=W2;
  w.d[0]=WqkvT; w.d[1]=WqkvT; w.d[2]=WqkvT; w.d[3]=WoT; w.d[4]=W1T; w.d[5]=W2T;
  convT_all_kernel<<<3072, 256, 0, stream>>>(w, flag);

  prep_kernel<<<BT, 256, 0, stream>>>(map_tok, agent_tok, light_tok, posf, flag,
                                      pe_b, out_f, out_b, qk_b);
  knn_kernel<<<1920, 256, 0, stream>>>(posf, idxb);

  const int RB = BT / 32; // 240 row blocks
  for (int l = 0; l < NLAYERS; l++) {
    gemm_qkv_kernel<<<dim3(RB, 3), 256, 0, stream>>>(
        qk_b, out_b, WqkvT + (size_t)l * 3 * DD * DD,
        pbuf + FB_BQ + l * DD, pbuf + FB_BK + l * DD, pbuf + FB_BV + l * DD, QKV);
    attn_kernel<<<BT, 256, 0, stream>>>(QKV, idxb, attnout);
    gemm_ln_kernel<DD, false><<<RB, 256, 0, stream>>>(
        attnout, WoT + (size_t)l * DD * DD, pbuf + FB_BO + l * DD,
        out_f, out_b, qk_b, pe_b, pbuf + FB_LN1S + l * DD, pbuf + FB_LN1B + l * DD);
    gemm_store_kernel<DD, true><<<dim3(RB, 4), 256, 0, stream>>>(
        out_b, W1T + (size_t)l * DD * FFD, pbuf + FB_B1 + l * FFD, hbuf, FFD);
    gemm_ln_kernel<FFD, true><<<RB, 256, 0, stream>>>(
        hbuf, W2T + (size_t)l * DD * FFD, pbuf + FB_B2 + l * DD,
        out_f, out_b, qk_b, pe_b, pbuf + FB_LN2S + l * DD, pbuf + FB_LN2B + l * DD);
  }

  writeout_kernel<<<BT, 256, 0, stream>>>(out_f, d_out, flag);
}